// Round 15
// baseline (117.301 us; speedup 1.0000x reference)
//
#include <hip/hip_runtime.h>

#define LOG2E 1.4426950408889634f

// async global->LDS DMA, 4 B per lane (64 contiguous LDS dwords per instruction;
// LDS dest = wave-uniform base + lane*4; global src is per-lane)
__device__ __forceinline__ void gload_lds(const float* g, float* l) {
    __builtin_amdgcn_global_load_lds(
        (const __attribute__((address_space(1))) void*)g,
        (__attribute__((address_space(3))) void*)l, 4, 0, 0);
}

struct SW {
    // per-gate pre-scaled weights (uniform -> SGPR). Gate k scale:
    // k==2 (g): -2*LOG2E, else -LOG2E, so sigma = rcp(1+exp2(z)) directly and
    // g's r = sigma(2x) encodes tanh. Cell tracked as C = -2L*c.
    float b1[4], W1[4], U1[4], V1[16];
    float b2[4], W2[4], U2[4], V2[16];
    float fw, fb;
};

__device__ __forceinline__ float sigm(float z) {      // z pre-scaled by -L
    return __builtin_amdgcn_rcpf(1.0f + __builtin_amdgcn_exp2f(z));
}

// One full fused step for one sequence on one lane (both layers + FC).
__device__ __forceinline__ float fstep(
    float a0, float a1, float a2, float a3, float xx,
    const SW& s, float& h1, float& C1, float& h2, float& C2)
{
    float z1[4];
#pragma unroll
    for (int k = 0; k < 4; k++) {
        float z = s.b1[k];
        z = fmaf(a0, s.V1[k],      z);
        z = fmaf(a1, s.V1[4 + k],  z);
        z = fmaf(a2, s.V1[8 + k],  z);
        z = fmaf(a3, s.V1[12 + k], z);
        z = fmaf(xx, s.W1[k], z);
        z = fmaf(h1, s.U1[k], z);
        z1[k] = z;
    }
    float i1 = sigm(z1[0]);
    float f1 = sigm(z1[1]);
    float rg1 = sigm(z1[2]);                            // sigma(2*zg)
    float gp1 = fmaf(-4.0f * LOG2E, rg1, 2.0f * LOG2E); // -2L*tanh(zg)
    float o1 = sigm(z1[3]);
    C1 = fmaf(f1, C1, i1 * gp1);                        // C1 = -2L*c1
    float th1 = fmaf(2.0f, sigm(C1), -1.0f);            // tanh(c1)
    h1 = o1 * th1;

    float z2[4];
#pragma unroll
    for (int k = 0; k < 4; k++) {
        float z = s.b2[k];
        z = fmaf(a0, s.V2[k],      z);
        z = fmaf(a1, s.V2[4 + k],  z);
        z = fmaf(a2, s.V2[8 + k],  z);
        z = fmaf(a3, s.V2[12 + k], z);
        z = fmaf(h1, s.W2[k], z);
        z = fmaf(h2, s.U2[k], z);
        z2[k] = z;
    }
    float i2 = sigm(z2[0]);
    float f2 = sigm(z2[1]);
    float rg2 = sigm(z2[2]);
    float gp2 = fmaf(-4.0f * LOG2E, rg2, 2.0f * LOG2E);
    float o2 = sigm(z2[3]);
    C2 = fmaf(f2, C2, i2 * gp2);
    float th2 = fmaf(2.0f, sigm(C2), -1.0f);
    h2 = o2 * th2;
    return fmaf(h2, s.fw, s.fb);
}

__global__ __launch_bounds__(256, 2) void pew_lstm_kernel(
    const float* __restrict__ input,
    const float* __restrict__ W1, const float* __restrict__ U1,
    const float* __restrict__ V1, const float* __restrict__ b1,
    const float* __restrict__ W2, const float* __restrict__ U2,
    const float* __restrict__ V2, const float* __restrict__ b2,
    const float* __restrict__ fcW, const float* __restrict__ fcb,
    float* __restrict__ out, int B)
{
    // per-wave double-buffered slab: [wave][dbuf][22 DMA x 64 dw] = 45056 B/block.
    // Layout: lane l's 20 dwords (4 steps x 5 ch, contiguous in its global row)
    // live at lds dw [l*22 .. l*22+19] (pad 2). Bank = 22l mod 32 -> 2 lanes per
    // bank (l, l+16) = 2-way = free. The DMA writes all 1408 dw linearly;
    // (r,d) = (L/22, L%22) source mapping, pad slots clamped in-bounds.
    __shared__ float lds[4][2][1408];

    const int lane  = threadIdx.x & 63;
    const int wslot = threadIdx.x >> 6;
    const int wv    = blockIdx.x * 4 + wslot;  // global wave id
    const int chunk = wv & 15;                 // 16 time chunks per sequence
    const int seq0  = (wv >> 4) << 6;          // 64 sequences per wave
    if (seq0 >= B) return;
    const int seq = seq0 + lane;

    SW s;
#pragma unroll
    for (int k = 0; k < 4; k++) {
        const float sc = (k == 2) ? (-2.0f * LOG2E) : (-LOG2E);
        s.b1[k] = sc * b1[k]; s.W1[k] = sc * W1[k]; s.U1[k] = sc * U1[k];
        s.b2[k] = sc * b2[k]; s.W2[k] = sc * W2[k]; s.U2[k] = sc * U2[k];
#pragma unroll
        for (int j = 0; j < 4; j++) {
            s.V1[j*4 + k] = sc * V1[j*4 + k];
            s.V2[j*4 + k] = sc * V2[j*4 + k];
        }
    }
    s.fw = fcW[0]; s.fb = fcb[0];

    // chunk geometry: outputs [64*chunk, 64*chunk+64); warmup 48 (chunk 0: 0)
    const int t0    = (chunk << 6) - (chunk ? 48 : 0);
    const int nslab = chunk ? 28 : 16;         // 4-step slabs
    const int sst   = chunk ? 12 : 0;          // first slab that stores

    // per-lane DMA source byte offsets, CONSTANT across slabs:
    // linear LDS dw L = 64*i + lane -> row r = L/22, dw d = L%22 within slab.
    int off22[22];
#pragma unroll
    for (int i = 0; i < 22; i++) {
        int L = 64 * i + lane;
        int r = L / 22;
        int d = L - 22 * r;
        off22[i] = r * 20480 + (d < 20 ? d * 4 : 0);   // pad: clamp in-bounds
    }

    const char* __restrict__ gblk = (const char*)(input + (size_t)seq0 * 5120);
    float* lb0 = &lds[wslot][0][0];
    float* lb1 = &lds[wslot][1][0];
    float* __restrict__ op = out + (size_t)seq * 1024;

    // prologue: DMA slab 0 into buf0 (slab s covers steps t0+4s .. t0+4s+3,
    // i.e. 80 contiguous bytes of each row starting at (t0+4s)*20)
    {
        const char* gs = gblk + (ptrdiff_t)t0 * 20;
#pragma unroll
        for (int i = 0; i < 22; i++)
            gload_lds((const float*)(gs + off22[i]), lb0 + i * 64);
    }

    float h1 = 0.f, C1 = 0.f, h2 = 0.f, C2 = 0.f;

#pragma unroll 1
    for (int sb = 0; sb < nslab; sb++) {
        float* cb = (sb & 1) ? lb1 : lb0;
        float* nb = (sb & 1) ? lb0 : lb1;
        if (sb + 1 < nslab) {
            const char* gs = gblk + (ptrdiff_t)(t0 + 4 * (sb + 1)) * 20;
#pragma unroll
            for (int i = 0; i < 22; i++)
                gload_lds((const float*)(gs + off22[i]), nb + i * 64);
            // wait for CURRENT slab's loads; keep next slab's 22 in flight
            asm volatile("s_waitcnt vmcnt(22)" ::: "memory");
        } else {
            asm volatile("s_waitcnt vmcnt(0)" ::: "memory");
        }
        __builtin_amdgcn_sched_barrier(0);

        // read my 20 dwords (10 x ds_read_b64, 2-way banks = free)
        const float2* lrow = (const float2*)(cb + lane * 22);
        float arr[20];
#pragma unroll
        for (int j = 0; j < 10; j++) {
            float2 v = lrow[j];
            arr[2*j] = v.x; arr[2*j + 1] = v.y;
        }
        float res[4];
#pragma unroll
        for (int st = 0; st < 4; st++)
            res[st] = fstep(arr[5*st+0], arr[5*st+1], arr[5*st+2],
                            arr[5*st+3], arr[5*st+4], s, h1, C1, h2, C2);
        if (sb >= sst) {
            float4* o4 = (float4*)(op + (t0 + 4 * sb));
            *o4 = make_float4(res[0], res[1], res[2], res[3]);
        }
    }
}

extern "C" void kernel_launch(void* const* d_in, const int* in_sizes, int n_in,
                              void* d_out, int out_size, void* d_ws, size_t ws_size,
                              hipStream_t stream) {
    const float* input = (const float*)d_in[0];
    const float* W1 = (const float*)d_in[1];
    const float* U1 = (const float*)d_in[2];
    const float* V1 = (const float*)d_in[3];
    const float* b1 = (const float*)d_in[4];
    const float* W2 = (const float*)d_in[5];
    const float* U2 = (const float*)d_in[6];
    const float* V2 = (const float*)d_in[7];
    const float* b2 = (const float*)d_in[8];
    const float* fcW = (const float*)d_in[9];
    const float* fcb = (const float*)d_in[10];
    float* out = (float*)d_out;

    int B = in_sizes[0] / (1024 * 5);
    // one thread per (seq, chunk): 16B threads; 64 seqs x 4 chunks per block
    int blocks = (16 * B + 255) / 256;
    hipLaunchKernelGGL(pew_lstm_kernel, dim3(blocks), dim3(256), 0, stream,
                       input, W1, U1, V1, b1, W2, U2, V2, b2, fcW, fcb, out, B);
}

// Round 16
// 62.758 us; speedup vs baseline: 1.8691x; 1.8691x over previous
//
#include <hip/hip_runtime.h>

#define LOG2E 1.4426950408889634f

// compile-time component pick from a float4 buffer (I is constant after unroll)
#define AV(B, I) ((I) % 4 == 0 ? (B)[(I)/4].x : (I) % 4 == 1 ? (B)[(I)/4].y \
                 : (I) % 4 == 2 ? (B)[(I)/4].z : (B)[(I)/4].w)

struct SW {
    // per-gate pre-scaled weights (uniform -> SGPR). Gate k scale:
    // k==2 (g): -2*LOG2E, else -LOG2E, so sigma = rcp(1+exp2(z)) directly and
    // g's r = sigma(2x) encodes tanh. Cell tracked as C = -2L*c.
    float b1[4], W1[4], U1[4], V1[16];
    float b2[4], W2[4], U2[4], V2[16];
    float fw, fb;
};

__device__ __forceinline__ float sigm(float z) {      // z pre-scaled by -L
    return __builtin_amdgcn_rcpf(1.0f + __builtin_amdgcn_exp2f(z));
}

// One full fused step for one sequence on one lane (both layers + FC).
__device__ __forceinline__ float fstep(
    float a0, float a1, float a2, float a3, float xx,
    const SW& s, float& h1, float& C1, float& h2, float& C2)
{
    float z1[4];
#pragma unroll
    for (int k = 0; k < 4; k++) {
        float z = s.b1[k];
        z = fmaf(a0, s.V1[k],      z);
        z = fmaf(a1, s.V1[4 + k],  z);
        z = fmaf(a2, s.V1[8 + k],  z);
        z = fmaf(a3, s.V1[12 + k], z);
        z = fmaf(xx, s.W1[k], z);
        z = fmaf(h1, s.U1[k], z);
        z1[k] = z;
    }
    float i1 = sigm(z1[0]);
    float f1 = sigm(z1[1]);
    float rg1 = sigm(z1[2]);                            // sigma(2*zg)
    float gp1 = fmaf(-4.0f * LOG2E, rg1, 2.0f * LOG2E); // -2L*tanh(zg)
    float o1 = sigm(z1[3]);
    C1 = fmaf(f1, C1, i1 * gp1);                        // C1 = -2L*c1
    float th1 = fmaf(2.0f, sigm(C1), -1.0f);            // tanh(c1)
    h1 = o1 * th1;

    float z2[4];
#pragma unroll
    for (int k = 0; k < 4; k++) {
        float z = s.b2[k];
        z = fmaf(a0, s.V2[k],      z);
        z = fmaf(a1, s.V2[4 + k],  z);
        z = fmaf(a2, s.V2[8 + k],  z);
        z = fmaf(a3, s.V2[12 + k], z);
        z = fmaf(h1, s.W2[k], z);
        z = fmaf(h2, s.U2[k], z);
        z2[k] = z;
    }
    float i2 = sigm(z2[0]);
    float f2 = sigm(z2[1]);
    float rg2 = sigm(z2[2]);
    float gp2 = fmaf(-4.0f * LOG2E, rg2, 2.0f * LOG2E);
    float o2 = sigm(z2[3]);
    C2 = fmaf(f2, C2, i2 * gp2);
    float th2 = fmaf(2.0f, sigm(C2), -1.0f);
    h2 = o2 * th2;
    return fmaf(h2, s.fw, s.fb);
}

// 8 steps from a 10x float4 register buffer; store 8 results if doStore.
__device__ __forceinline__ void compute8(
    const float4 (&buf)[10], const SW& s,
    float& h1, float& C1, float& h2, float& C2,
    float* op, bool doStore)
{
    float res[8];
#pragma unroll
    for (int j = 0; j < 8; j++) {
        res[j] = fstep(AV(buf, 5*j+0), AV(buf, 5*j+1), AV(buf, 5*j+2),
                       AV(buf, 5*j+3), AV(buf, 5*j+4), s, h1, C1, h2, C2);
    }
    if (doStore) {
        float4* o4 = (float4*)op;
        o4[0] = make_float4(res[0], res[1], res[2], res[3]);
        o4[1] = make_float4(res[4], res[5], res[6], res[7]);
    }
}

__global__ __launch_bounds__(256, 1) void pew_lstm_kernel(
    const float* __restrict__ input,
    const float* __restrict__ W1, const float* __restrict__ U1,
    const float* __restrict__ V1, const float* __restrict__ b1,
    const float* __restrict__ W2, const float* __restrict__ U2,
    const float* __restrict__ V2, const float* __restrict__ b2,
    const float* __restrict__ fcW, const float* __restrict__ fcb,
    float* __restrict__ out, int B)
{
    const int lane = threadIdx.x & 63;
    const int wv   = (blockIdx.x * blockDim.x + threadIdx.x) >> 6; // global wave
    const int chunk = wv & 7;                 // 8 time chunks per sequence
    const int seq   = ((wv >> 3) << 6) + lane;
    if (seq >= B) return;

    SW s;
#pragma unroll
    for (int k = 0; k < 4; k++) {
        const float sc = (k == 2) ? (-2.0f * LOG2E) : (-LOG2E);
        s.b1[k] = sc * b1[k]; s.W1[k] = sc * W1[k]; s.U1[k] = sc * U1[k];
        s.b2[k] = sc * b2[k]; s.W2[k] = sc * W2[k]; s.U2[k] = sc * U2[k];
#pragma unroll
        for (int j = 0; j < 4; j++) {
            s.V1[j*4 + k] = sc * V1[j*4 + k];
            s.V2[j*4 + k] = sc * V2[j*4 + k];
        }
    }
    s.fw = fcW[0]; s.fb = fcb[0];

    // chunk geometry: outputs [128*chunk, 128*chunk+128); warmup 64 (chunk 0: 0)
    const int t0   = (chunk << 7) - (chunk ? 64 : 0);
    const int nblk = chunk ? 24 : 16;          // 8-step blocks (multiple of 4)
    const int kst  = chunk ? 8 : 0;            // first block that stores

    const float4* __restrict__ p =
        reinterpret_cast<const float4*>(input + (size_t)seq * 5120 + (size_t)t0 * 5);
    float* __restrict__ op = out + (size_t)seq * 1024 + t0;

    // 4-deep register prefetch ring: ~3 block-loads (30 float4, ~8 lines) in
    // flight per wave during every compute -> fills the ~900cy HBM latency pipe
    // (R13's single-buffer kept only ~2-3 lines outstanding = the 44% stall).
    float4 ring0[10], ring1[10], ring2[10], ring3[10];
#pragma unroll
    for (int q = 0; q < 10; q++) ring0[q] = p[q];
#pragma unroll
    for (int q = 0; q < 10; q++) ring1[q] = p[10 + q];
#pragma unroll
    for (int q = 0; q < 10; q++) ring2[q] = p[20 + q];
#pragma unroll
    for (int q = 0; q < 10; q++) ring3[q] = p[30 + q];
    __builtin_amdgcn_sched_barrier(0);

    float h1 = 0.f, C1 = 0.f, h2 = 0.f, C2 = 0.f;

#pragma unroll 1
    for (int k = 0; k < nblk; k += 4) {
        compute8(ring0, s, h1, C1, h2, C2, op + 8 * k, k >= kst);
        if (k + 4 < nblk) {
#pragma unroll
            for (int q = 0; q < 10; q++) ring0[q] = p[10 * (k + 4) + q];
        }
        __builtin_amdgcn_sched_barrier(0);
        compute8(ring1, s, h1, C1, h2, C2, op + 8 * (k + 1), k + 1 >= kst);
        if (k + 5 < nblk) {
#pragma unroll
            for (int q = 0; q < 10; q++) ring1[q] = p[10 * (k + 5) + q];
        }
        __builtin_amdgcn_sched_barrier(0);
        compute8(ring2, s, h1, C1, h2, C2, op + 8 * (k + 2), k + 2 >= kst);
        if (k + 6 < nblk) {
#pragma unroll
            for (int q = 0; q < 10; q++) ring2[q] = p[10 * (k + 6) + q];
        }
        __builtin_amdgcn_sched_barrier(0);
        compute8(ring3, s, h1, C1, h2, C2, op + 8 * (k + 3), k + 3 >= kst);
        if (k + 7 < nblk) {
#pragma unroll
            for (int q = 0; q < 10; q++) ring3[q] = p[10 * (k + 7) + q];
        }
        __builtin_amdgcn_sched_barrier(0);
    }
}

extern "C" void kernel_launch(void* const* d_in, const int* in_sizes, int n_in,
                              void* d_out, int out_size, void* d_ws, size_t ws_size,
                              hipStream_t stream) {
    const float* input = (const float*)d_in[0];
    const float* W1 = (const float*)d_in[1];
    const float* U1 = (const float*)d_in[2];
    const float* V1 = (const float*)d_in[3];
    const float* b1 = (const float*)d_in[4];
    const float* W2 = (const float*)d_in[5];
    const float* U2 = (const float*)d_in[6];
    const float* V2 = (const float*)d_in[7];
    const float* b2 = (const float*)d_in[8];
    const float* fcW = (const float*)d_in[9];
    const float* fcb = (const float*)d_in[10];
    float* out = (float*)d_out;

    int B = in_sizes[0] / (1024 * 5);
    // one thread per (seq, chunk): 8B threads total
    int blocks = (8 * B + 255) / 256;
    hipLaunchKernelGGL(pew_lstm_kernel, dim3(blocks), dim3(256), 0, stream,
                       input, W1, U1, V1, b1, W2, U2, V2, b2, fcW, fcb, out, B);
}